// Round 1
// baseline (60.656 us; speedup 1.0000x reference)
//
#include <hip/hip_runtime.h>
#include <cstdint>
#include <cstddef>

// Problem constants
#define B_ 256
#define D_ 512
#define P_ 128
#define E_ 128

typedef unsigned short u16;
typedef __bf16  bf16x8_t __attribute__((ext_vector_type(8)));
typedef float   f32x4_t  __attribute__((ext_vector_type(4)));
typedef u16     u16x8_t  __attribute__((ext_vector_type(8)));

__device__ __forceinline__ u16 f2bf(float f) {
  // round-to-nearest-even f32 -> bf16 (finite inputs)
  union { float f; unsigned int u; } c; c.f = f;
  unsigned int u = c.u;
  unsigned int r = (u + 0x7FFFu + ((u >> 16) & 1u)) >> 16;
  return (u16)r;
}

// ---------------------------------------------------------------------------
// Pass 1: transpose + convert f32 -> bf16.
// Treat src as [outer][R=512 rows][C=128 cols] f32.
// dst element for (o, r, c) lives at: c*dst_row_stride + o*dst_outer_stride + r
//   x: outer=b (256), cols=p  -> xT[p][b][d]: row_stride=256*512, outer_stride=512
//   W: outer=p (128), cols=e  -> Wt[p][e][d]: row_stride=512,     outer_stride=128*512
// ---------------------------------------------------------------------------
__global__ __launch_bounds__(256) void transpose_cvt_kernel(
    const float* __restrict__ src, u16* __restrict__ dst,
    size_t dst_row_stride, size_t dst_outer_stride) {
  __shared__ float tile[64][65];  // +1 pad: conflict-free column reads

  const int o  = blockIdx.x;
  const int r0 = blockIdx.y * 64;
  const int c0 = blockIdx.z * 64;
  const int t  = threadIdx.x;

  const float* s = src + (size_t)o * D_ * 128 + (size_t)r0 * 128 + c0;

  // load 64x64 f32 tile, coalesced float4 rows
  {
    const int lr = t >> 4;          // 0..15
    const int lc = (t & 15) * 4;    // 0..60
    #pragma unroll
    for (int it = 0; it < 4; ++it) {
      const int r = lr + it * 16;
      const float4 v = *reinterpret_cast<const float4*>(s + (size_t)r * 128 + lc);
      tile[r][lc + 0] = v.x; tile[r][lc + 1] = v.y;
      tile[r][lc + 2] = v.z; tile[r][lc + 3] = v.w;
    }
  }
  __syncthreads();

  // write transposed rows (c-major), bf16x8 (16B) chunks, coalesced
  {
    const int wc = t >> 3;          // 0..31 (col within tile)
    const int wd = (t & 7) * 8;     // 0..56 (row chunk base)
    #pragma unroll
    for (int it = 0; it < 2; ++it) {
      const int c = wc + it * 32;
      u16x8_t pk;
      #pragma unroll
      for (int j = 0; j < 8; ++j) pk[j] = f2bf(tile[wd + j][c]);
      *reinterpret_cast<u16x8_t*>(dst + (size_t)(c0 + c) * dst_row_stride +
                                  (size_t)o * dst_outer_stride + r0 + wd) = pk;
    }
  }
}

// ---------------------------------------------------------------------------
// Pass 2: per-p bf16 TN GEMM (m97-style 128x128 tile, BK=32, 4 waves,
// global_load_lds width-16 staging, 16x16x32 MFMA, 4x4 frags per wave).
//   A = xT[p][b][d]  (M=b, K=d, K-contiguous)
//   B = Wt[p][e][d]  (N=e, K=d, K-contiguous)
//   out[b][e][p] += bias[p][e]
// Grid: 256 WGs, XCD-swizzled: xcd = wg&7 owns p in [16*xcd, 16*xcd+16),
// both b-tiles — merges 512B-strided out writes in one XCD's L2 and shares Wt.
// ---------------------------------------------------------------------------
__global__ __launch_bounds__(256) void gemm_kernel(
    const u16* __restrict__ xT, const u16* __restrict__ Wt,
    const float* __restrict__ bias, float* __restrict__ out) {
  __shared__ __attribute__((aligned(16))) u16 As[128 * 32];
  __shared__ __attribute__((aligned(16))) u16 Bs[128 * 32];

  const int wg  = blockIdx.x;
  const int xcd = wg & 7;
  const int i   = wg >> 3;            // 0..31
  const int p   = xcd * 16 + (i & 15);
  const int bt  = i >> 4;             // 0..1
  const int b0  = bt * 128;

  const int t    = threadIdx.x;
  const int lane = t & 63;
  const int wv   = t >> 6;            // wave 0..3
  const int wr   = wv >> 1;           // wave row (2x2 wave grid)
  const int wc   = wv & 1;            // wave col

  const u16* Ag = xT + (size_t)p * (B_ * D_) + (size_t)b0 * D_;
  const u16* Bg = Wt + (size_t)p * (E_ * D_);

  // staging chunk ids: 16B chunks; tile = 512 chunks, 256 threads x2
  const int c1 = t, c2 = t + 256;
  const int r1 = c1 >> 2, h1 = (c1 & 3) * 8;
  const int r2 = c2 >> 2, h2 = (c2 & 3) * 8;
  // wave-uniform LDS bases (elems)
  u16* lA1 = &As[(size_t)wv * 512];
  u16* lA2 = &As[2048 + (size_t)wv * 512];
  u16* lB1 = &Bs[(size_t)wv * 512];
  u16* lB2 = &Bs[2048 + (size_t)wv * 512];

  f32x4_t acc[4][4] = {};

  const int fr = lane & 15;
  const int fk = (lane >> 4) * 8;

  for (int kt = 0; kt < 16; ++kt) {
    const int d0 = kt * 32;
    // ---- stage A (8KB) + B (8KB) via direct global->LDS, 16B/lane ----
    __builtin_amdgcn_global_load_lds(
        (const __attribute__((address_space(1))) void*)(Ag + (size_t)r1 * D_ + d0 + h1),
        (__attribute__((address_space(3))) void*)lA1, 16, 0, 0);
    __builtin_amdgcn_global_load_lds(
        (const __attribute__((address_space(1))) void*)(Ag + (size_t)r2 * D_ + d0 + h2),
        (__attribute__((address_space(3))) void*)lA2, 16, 0, 0);
    __builtin_amdgcn_global_load_lds(
        (const __attribute__((address_space(1))) void*)(Bg + (size_t)r1 * D_ + d0 + h1),
        (__attribute__((address_space(3))) void*)lB1, 16, 0, 0);
    __builtin_amdgcn_global_load_lds(
        (const __attribute__((address_space(1))) void*)(Bg + (size_t)r2 * D_ + d0 + h2),
        (__attribute__((address_space(3))) void*)lB2, 16, 0, 0);
    __syncthreads();   // compiler drains vmcnt(0) before barrier -> LDS valid

    bf16x8_t af[4], bf[4];
    #pragma unroll
    for (int ii = 0; ii < 4; ++ii)
      af[ii] = *reinterpret_cast<const bf16x8_t*>(&As[(wr * 64 + ii * 16 + fr) * 32 + fk]);
    #pragma unroll
    for (int jj = 0; jj < 4; ++jj)
      bf[jj] = *reinterpret_cast<const bf16x8_t*>(&Bs[(wc * 64 + jj * 16 + fr) * 32 + fk]);
    #pragma unroll
    for (int ii = 0; ii < 4; ++ii)
      #pragma unroll
      for (int jj = 0; jj < 4; ++jj)
        acc[ii][jj] = __builtin_amdgcn_mfma_f32_16x16x32_bf16(af[ii], bf[jj], acc[ii][jj], 0, 0, 0);
    __syncthreads();
  }

  // ---- epilogue: C/D layout col=lane&15, row=(lane>>4)*4+reg (m89-verified) ----
  const int q4 = (lane >> 4) * 4;
  #pragma unroll
  for (int jj = 0; jj < 4; ++jj) {
    const int e  = wc * 64 + jj * 16 + fr;
    const float bv = bias[p * E_ + e];
    #pragma unroll
    for (int ii = 0; ii < 4; ++ii) {
      const int r0 = b0 + wr * 64 + ii * 16 + q4;
      #pragma unroll
      for (int rg = 0; rg < 4; ++rg) {
        out[((size_t)(r0 + rg) * E_ + e) * P_ + p] = acc[ii][jj][rg] + bv;
      }
    }
  }
}

// ---------------------------------------------------------------------------
// Fallback (only if workspace is too small): naive but correct.
// ---------------------------------------------------------------------------
__global__ __launch_bounds__(256) void naive_kernel(
    const float* __restrict__ x, const float* __restrict__ W,
    const float* __restrict__ bias, float* __restrict__ out) {
  const size_t idx = (size_t)blockIdx.x * 256 + threadIdx.x;
  const int p = (int)(idx & 127);
  const int e = (int)((idx >> 7) & 127);
  const int b = (int)(idx >> 14);
  float acc = bias[p * E_ + e];
  const float* xp = x + (size_t)b * D_ * P_ + p;
  const float* wp = W + (size_t)p * D_ * E_ + e;
  for (int d = 0; d < D_; ++d) acc += xp[(size_t)d * P_] * wp[(size_t)d * E_];
  out[idx] = acc;
}

extern "C" void kernel_launch(void* const* d_in, const int* in_sizes, int n_in,
                              void* d_out, int out_size, void* d_ws, size_t ws_size,
                              hipStream_t stream) {
  (void)in_sizes; (void)n_in; (void)out_size;
  const float* x    = (const float*)d_in[0];   // [B,D,P] f32
  const float* W    = (const float*)d_in[1];   // [P,D,E] f32
  const float* bias = (const float*)d_in[2];   // [P,E]   f32
  float* out = (float*)d_out;                  // [B,E,P] f32

  const size_t xT_bytes = (size_t)P_ * B_ * D_ * 2;   // 32 MiB
  const size_t Wt_bytes = (size_t)P_ * E_ * D_ * 2;   // 16 MiB

  if (ws_size < xT_bytes + Wt_bytes) {
    naive_kernel<<<dim3((B_ * E_ * P_) / 256), dim3(256), 0, stream>>>(x, W, bias, out);
    return;
  }

  u16* xT = (u16*)d_ws;                                 // [P][B][D] bf16
  u16* Wt = (u16*)((char*)d_ws + xT_bytes);             // [P][E][D] bf16

  // x: outer=b(256), dst xT[p][b][d]
  transpose_cvt_kernel<<<dim3(B_, 8, 2), 256, 0, stream>>>(
      x, xT, (size_t)B_ * D_, (size_t)D_);
  // W: outer=p(128), dst Wt[p][e][d]
  transpose_cvt_kernel<<<dim3(P_, 8, 2), 256, 0, stream>>>(
      W, Wt, (size_t)D_, (size_t)E_ * D_);

  gemm_kernel<<<dim3(256), 256, 0, stream>>>(xT, Wt, bias, out);
}